// Round 5
// baseline (161.853 us; speedup 1.0000x reference)
//
#include <hip/hip_runtime.h>

// LSS view transform, segment-gather formulation, sharded + wave-run binning.
// out[b,c,cell] = sum_{(pix,d)->cell} img[b,c,pix] * dp[b,d,pix]
// Round-13 (base = round-12, 147.9us):
//  - K5: fixed 64-entry chunks -> cell-aligned <=64-entry segments built by
//    k_scan (seg bases via 2nd LDS scan, no serialized atomic). Whole-cell
//    segments flush with plain float2 stores; atomics only for split cells.
//    Kills ~6.1M flush-atomic dwords (~20us at ~128 RMW/cyc chip-wide).
//  - k_shardbase folded away: k_reduce leaves per-(shard,cell) local prefix
//    in hist2; k_fill adds offs[gcell]. One fewer dispatch.
//  - entries packed as one dword (pix | w16<<13) instead of int+short.
//  - sharded hist2 atomics in count/fill PRESERVED (round-11 lesson).
constexpr int IMG_H = 48, IMG_W = 160;
constexpr int HW    = IMG_H * IMG_W;          // 7680
constexpr int BEV_H = 128, BEV_W = 128;
constexpr int NCELL = BEV_H * BEV_W;          // 16384 per batch
constexpr int C_DIM = 128, D_DIM = 64, B_DIM = 2;
constexpr int NCELL_TOT = B_DIM * NCELL;      // 32768
constexpr int NPIX_TOT  = B_DIM * HW;         // 15360
constexpr int NPTS      = NPIX_TOT * D_DIM;   // 983040
constexpr int SEGLEN    = 64;
constexpr int MAX_SEGS  = NCELL_TOT + NPTS / SEGLEN;   // 48128
constexpr int NSHARD = 16;
constexpr int CNT_BLOCKS = NPTS / 256;        // 3840
constexpr int TRN_BLOCKS = (HW / 32) * (C_DIM / 32) * B_DIM;  // 1920
constexpr float X_MIN = -51.2f, Y_MIN = -51.2f;
constexpr float RES_X = 102.4f / 128.0f;
constexpr float RES_Y = 102.4f / 128.0f;

typedef _Float16 half2v __attribute__((ext_vector_type(2)));

// ---- ws layout (4-byte words), ~26.2 MB total (ws is ~256 MB) ----
constexpr size_t WS_IMG_T  = 0;                                        // half[B*HW*C]
constexpr size_t WS_HIST2  = WS_IMG_T + (size_t)B_DIM * HW * C_DIM / 2;// int[16*32768] [memset]
constexpr size_t WS_OUT_T  = WS_HIST2 + (size_t)NSHARD * NCELL_TOT;    // float[32768*128] [memset, adjacent]
constexpr size_t WS_HIST   = WS_OUT_T + (size_t)NCELL_TOT * C_DIM;     // int[32768]
constexpr size_t WS_OFFS   = WS_HIST + NCELL_TOT;                      // int[32769]+pad
constexpr size_t WS_SEGCNT = WS_OFFS + NCELL_TOT + 4;                  // int[4]
constexpr size_t WS_SEGS   = WS_SEGCNT + 4;                            // uint2[MAX_SEGS] (8B-aligned)
constexpr size_t WS_EPW    = WS_SEGS + (size_t)MAX_SEGS * 2;           // uint[NPTS]
constexpr size_t MEMSET_WORDS = (size_t)NSHARD * NCELL_TOT + (size_t)NCELL_TOT * C_DIM;

__device__ inline int point_shard(int tid) {
    return ((tid >> 2) + (tid >> 8)) & (NSHARD - 1);   // deterministic in tid
}

__device__ inline void make_ray(const float* __restrict__ K, int b, float gx, float gy,
                                float& rx, float& ry, float& rz) {
    const float* Kb = K + b * 9;
    const float a00 = Kb[0], a01 = Kb[1], a02 = Kb[2];
    const float a10 = Kb[3], a11 = Kb[4], a12 = Kb[5];
    const float a20 = Kb[6], a21 = Kb[7], a22 = Kb[8];
    const float det = a00 * (a11 * a22 - a12 * a21)
                    - a01 * (a10 * a22 - a12 * a20)
                    + a02 * (a10 * a21 - a11 * a20);
    const float inv = 1.0f / det;
    const float i00 =  (a11 * a22 - a12 * a21) * inv;
    const float i01 = -(a01 * a22 - a02 * a21) * inv;
    const float i02 =  (a01 * a12 - a02 * a11) * inv;
    const float i10 = -(a10 * a22 - a12 * a20) * inv;
    const float i11 =  (a00 * a22 - a02 * a20) * inv;
    const float i12 = -(a00 * a12 - a02 * a10) * inv;
    const float i20 =  (a10 * a21 - a11 * a20) * inv;
    const float i21 = -(a00 * a21 - a01 * a20) * inv;
    const float i22 =  (a00 * a11 - a01 * a10) * inv;
    rx = i00 * gx + i01 * gy + i02;
    ry = i10 * gx + i11 * gy + i12;
    rz = i20 * gx + i21 * gy + i22;
}

// Returns global cell id (b*NCELL + cell) or -1. tid = ((b*D + d)*HW + pix).
__device__ inline int point_gcell(int tid, const float* __restrict__ dv,
                                  const float* __restrict__ K,
                                  const float* __restrict__ T) {
    const int pix = tid % HW;
    const int bd  = tid / HW;
    const int d   = bd % D_DIM;
    const int b   = bd / D_DIM;
    const int h = pix / IMG_W, w = pix % IMG_W;
    float rx, ry, rz;
    make_ray(K, b, (float)w, (float)h, rx, ry, rz);
    const float* Tb = T + b * 16;
    const float dep = dv[d];                       // wave-uniform
    const float px = dep * rx, py = dep * ry, pz = dep * rz;
    const float x = Tb[0] * px + Tb[1] * py + Tb[2]  * pz + Tb[3];
    const float y = Tb[4] * px + Tb[5] * py + Tb[6]  * pz + Tb[7];
    const float z = Tb[8] * px + Tb[9] * py + Tb[10] * pz + Tb[11];
    const int bx = (int)((x - X_MIN) / RES_X);     // truncate-toward-zero == astype(int32)
    const int by = (int)((y - Y_MIN) / RES_Y);
    const bool valid = (bx >= 0) && (bx < BEV_W) && (by >= 0) && (by < BEV_H) && (z > 0.0f);
    return valid ? (b * NCELL + by * BEV_W + bx) : -1;
}

// Wave-run helpers: lanes are consecutive pixels -> equal-cell runs.
__device__ inline bool wave_runs(int gcell, int lane, int& run_len, int& leader_idx) {
    const int left = __shfl_up(gcell, 1);          // width 64
    const bool is_leader = (lane == 0) || (left != gcell);
    const unsigned long long lmask = __ballot(is_leader);
    const unsigned long long rest = (lane == 63) ? 0ULL : (lmask >> (lane + 1));
    const int f = __ffsll((unsigned long long)rest);   // 1+idx or 0
    run_len = f ? f : (64 - lane);
    const unsigned long long below =
        lmask & ((lane == 63) ? ~0ULL : ((1ULL << (lane + 1)) - 1ULL));
    leader_idx = 63 - __clzll((long long)below);
    return is_leader;
}

// ---- K1: fused {sharded count (blocks 0..3839)} + {transpose/fp16 (3840..5759)} ----
__global__ __launch_bounds__(256) void k_prep(const float* __restrict__ img,
                                              _Float16* __restrict__ img_t,
                                              const float* __restrict__ dv,
                                              const float* __restrict__ K,
                                              const float* __restrict__ T,
                                              int* __restrict__ hist2) {
    __shared__ float tile[32][33];
    if (blockIdx.x < CNT_BLOCKS) {
        const int tid = blockIdx.x * 256 + threadIdx.x;   // < NPTS (exact)
        const int gcell = point_gcell(tid, dv, K, T);
        const int lane = threadIdx.x & 63;
        int run_len, leader_idx;
        const bool lead = wave_runs(gcell, lane, run_len, leader_idx);
        if (lead && gcell >= 0)
            atomicAdd(&hist2[(size_t)point_shard(tid) * NCELL_TOT + gcell], run_len);
    } else {
        const int bi = blockIdx.x - CNT_BLOCKS;
        const int px_t = bi % (HW / 32);
        const int c_t  = (bi / (HW / 32)) % (C_DIM / 32);
        const int b    = bi / ((HW / 32) * (C_DIM / 32));
        const int tx = threadIdx.x & 31, ty = threadIdx.x >> 5;   // (32,8)
        const int pix0 = px_t * 32, c0 = c_t * 32;
        #pragma unroll
        for (int j = 0; j < 32; j += 8)
            tile[ty + j][tx] = img[((size_t)(b * C_DIM + c0 + ty + j)) * HW + pix0 + tx];
        __syncthreads();
        #pragma unroll
        for (int j = 0; j < 32; j += 8)
            img_t[((size_t)(b * HW + pix0 + ty + j)) * C_DIM + c0 + tx] =
                (_Float16)tile[tx][ty + j];
    }
}

// ---- K2: reduce shards -> per-cell totals; hist2 becomes per-cell LOCAL
// shard prefix in place (fill adds offs[cell] later). ----
__global__ __launch_bounds__(256) void k_reduce(int* __restrict__ hist2,
                                                int* __restrict__ hist) {
    const int cell = blockIdx.x * 256 + threadIdx.x;  // 128 blocks exact
    int run = 0;
    #pragma unroll
    for (int sh = 0; sh < NSHARD; ++sh) {
        const size_t idx = (size_t)sh * NCELL_TOT + cell;
        const int c = hist2[idx];
        hist2[idx] = run;           // local exclusive prefix within cell
        run += c;
    }
    hist[cell] = run;
}

// ---- K3: scan (offs) + segment build (seg bases via 2nd LDS scan) ----
__global__ __launch_bounds__(1024) void k_scan(const int* __restrict__ hist,
                                               int* __restrict__ offs,
                                               int* __restrict__ seg_cnt,
                                               uint2* __restrict__ segs) {
    __shared__ int lds[1024];
    const int t = threadIdx.x;
    int h[32];
    int s = 0;
    const int base = t * 32;
    #pragma unroll
    for (int k = 0; k < 32; ++k) { h[k] = hist[base + k]; s += h[k]; }
    lds[t] = s;
    __syncthreads();
    for (int off = 1; off < 1024; off <<= 1) {
        int v = (t >= off) ? lds[t - off] : 0;
        __syncthreads();
        lds[t] += v;
        __syncthreads();
    }
    const int run0 = lds[t] - s;   // exclusive entry base for this thread's cells
    if (t == 1023) offs[NCELL_TOT] = lds[1023];
    int run = run0;
    int nseg = 0;
    #pragma unroll
    for (int k = 0; k < 32; ++k) {
        offs[base + k] = run;
        run += h[k];
        nseg += (h[k] + SEGLEN - 1) >> 6;
    }
    // second scan: segment bases (no serialized atomic)
    __syncthreads();
    lds[t] = nseg;
    __syncthreads();
    for (int off = 1; off < 1024; off <<= 1) {
        int v = (t >= off) ? lds[t - off] : 0;
        __syncthreads();
        lds[t] += v;
        __syncthreads();
    }
    int sbase = lds[t] - nseg;
    if (t == 1023) seg_cnt[0] = lds[1023];
    run = run0;
    for (int k = 0; k < 32; ++k) {
        const int cnt = h[k];
        if (cnt > 0) {
            const unsigned whole = (cnt <= SEGLEN) ? 1u : 0u;
            for (int done = 0; done < cnt; done += SEGLEN) {
                const unsigned len = (unsigned)min(SEGLEN, cnt - done);
                segs[sbase++] = make_uint2((unsigned)(run + done),
                                           (unsigned)(base + k) | (len << 15) | (whole << 22));
            }
        }
        run += cnt;
    }
}

// ---- K4: fill packed entries; leader reserves span via offs + local cursor ----
__global__ __launch_bounds__(256) void k_fill(const float* __restrict__ dp,
                                              const float* __restrict__ dv,
                                              const float* __restrict__ K,
                                              const float* __restrict__ T,
                                              const int* __restrict__ offs,
                                              int* __restrict__ cursor2,   // = hist2 (local prefix)
                                              unsigned* __restrict__ epw) {
    const int tid = blockIdx.x * 256 + threadIdx.x;   // < NPTS (exact)
    const int gcell = point_gcell(tid, dv, K, T);
    const int lane = threadIdx.x & 63;
    int run_len, leader_idx;
    const bool lead = wave_runs(gcell, lane, run_len, leader_idx);
    int base = 0;
    if (lead && gcell >= 0)
        base = offs[gcell]
             + atomicAdd(&cursor2[(size_t)point_shard(tid) * NCELL_TOT + gcell], run_len);
    base = __shfl(base, leader_idx);                  // broadcast my run's base
    if (gcell < 0) return;
    const int slot = base + (lane - leader_idx);      // contiguous, coalesced writes
    const float p = dp[tid];                          // coalesced
    epw[slot] = (unsigned)(tid % HW) | (__float2uint_rn(p * 65535.0f) << 13);
}

// ---- K5: segment gather. One wave per <=64-entry single-cell segment.
// readlane broadcasts (SGPR path); 16-entry groups, 2-deep pipeline.
// Whole-cell segments: plain coalesced float2 store. Split cells: atomics.
__global__ __launch_bounds__(256) void k_seg_gather(
    const _Float16* __restrict__ img_t,
    const int* __restrict__ seg_cnt,
    const uint2* __restrict__ segs,
    const unsigned* __restrict__ epw,
    float* __restrict__ out_t)
{
    const int nseg = seg_cnt[0];
    const int sidx = blockIdx.x * 4 + (threadIdx.x >> 6);
    if (sidx >= nseg) return;
    const int lane = threadIdx.x & 63;
    const uint2 sg = segs[sidx];
    const int start  = (int)sg.x;
    const int gcell  = (int)(sg.y & 32767u);
    const int len    = (int)((sg.y >> 15) & 127u);
    const bool whole = (sg.y >> 22) & 1u;
    const int bb = gcell >> 14;                       // batch

    unsigned pw = 0;                                  // pad: pix 0, w 0 (harmless)
    if (lane < len) pw = epw[start + lane];

    const int c2 = lane * 2;                          // channels c2, c2+1
    const _Float16* rowbase = img_t + ((size_t)bb * HW) * C_DIM + c2;
    float2 acc = make_float2(0.0f, 0.0f);

#define LOAD16(G, V)                                                             \
    do {                                                                         \
        _Pragma("unroll")                                                        \
        for (int j = 0; j < 16; ++j) {                                           \
            const unsigned sk =                                                  \
                (unsigned)__builtin_amdgcn_readlane((int)pw, (G) * 16 + j);      \
            V[j] = *reinterpret_cast<const half2v*>(                             \
                rowbase + (size_t)(sk & 8191u) * C_DIM);                         \
        }                                                                        \
    } while (0)

#define ACC16(G, V)                                                              \
    do {                                                                         \
        _Pragma("unroll")                                                        \
        for (int j = 0; j < 16; ++j) {                                           \
            const unsigned sk =                                                  \
                (unsigned)__builtin_amdgcn_readlane((int)pw, (G) * 16 + j);      \
            const float w = (float)(sk >> 13);                                   \
            acc.x = fmaf((float)V[j][0], w, acc.x);                              \
            acc.y = fmaf((float)V[j][1], w, acc.y);                              \
        }                                                                        \
    } while (0)

    half2v va[16], vb[16];
    // up to 4 x 16-entry groups, 2-deep modulo pipeline, wave-uniform guards
    LOAD16(0, va);
    if (len > 16) LOAD16(1, vb);
    ACC16(0, va);
    if (len > 16) {
        if (len > 32) LOAD16(2, va);
        ACC16(1, vb);
        if (len > 32) {
            if (len > 48) LOAD16(3, vb);
            ACC16(2, va);
            if (len > 48) ACC16(3, vb);
        }
    }
#undef LOAD16
#undef ACC16

    const float scale = 1.0f / 65535.0f;
    const float2 res = make_float2(acc.x * scale, acc.y * scale);
    float* o = &out_t[(size_t)gcell * C_DIM + c2];
    if (whole) {
        *reinterpret_cast<float2*>(o) = res;          // sole owner: plain store
    } else {
        atomicAdd(o, res.x);
        atomicAdd(o + 1, res.y);
    }
}

// ---- K6: untranspose out_t[b][cell][c] -> out[b][c][cell] ----
__global__ __launch_bounds__(256) void k_untranspose(const float* __restrict__ out_t,
                                                     float* __restrict__ out) {
    __shared__ float tile[32][33];
    const int b = blockIdx.z;
    const int tx = threadIdx.x, ty = threadIdx.y;      // block (32, 8)
    const int cell0 = blockIdx.x * 32, c0 = blockIdx.y * 32;
    const float* src = out_t + (size_t)b * NCELL * C_DIM;
    #pragma unroll
    for (int j = 0; j < 32; j += 8)                    // read: c contiguous
        tile[ty + j][tx] = src[((size_t)(cell0 + ty + j)) * C_DIM + c0 + tx];
    __syncthreads();
    #pragma unroll
    for (int j = 0; j < 32; j += 8)                    // write: cell contiguous
        out[((size_t)(b * C_DIM + c0 + ty + j)) * NCELL + cell0 + tx] = tile[tx][ty + j];
}

extern "C" void kernel_launch(void* const* d_in, const int* in_sizes, int n_in,
                              void* d_out, int out_size, void* d_ws, size_t ws_size,
                              hipStream_t stream) {
    const float* img = (const float*)d_in[0];
    const float* dp  = (const float*)d_in[1];
    const float* dv  = (const float*)d_in[2];
    const float* K   = (const float*)d_in[3];
    const float* T   = (const float*)d_in[4];
    float* out = (float*)d_out;

    _Float16* img_t = (_Float16*)d_ws;                  // WS_IMG_T == 0
    int*   hist2   = (int*)d_ws + WS_HIST2;
    float* out_t   = (float*)d_ws + WS_OUT_T;
    int*   hist    = (int*)d_ws + WS_HIST;
    int*   offs    = (int*)d_ws + WS_OFFS;
    int*   seg_cnt = (int*)d_ws + WS_SEGCNT;
    uint2* segs    = (uint2*)((int*)d_ws + WS_SEGS);
    unsigned* epw  = (unsigned*)((int*)d_ws + WS_EPW);
    (void)ws_size;

    // zero hist2 + out_t in one contiguous memset (~18.9 MB)
    hipMemsetAsync(hist2, 0, MEMSET_WORDS * sizeof(int), stream);

    k_prep<<<CNT_BLOCKS + TRN_BLOCKS, 256, 0, stream>>>(img, img_t, dv, K, T, hist2);
    k_reduce<<<NCELL_TOT / 256, 256, 0, stream>>>(hist2, hist);
    k_scan<<<1, 1024, 0, stream>>>(hist, offs, seg_cnt, segs);
    k_fill<<<NPTS / 256, 256, 0, stream>>>(dp, dv, K, T, offs, hist2, epw);
    k_seg_gather<<<MAX_SEGS / 4, 256, 0, stream>>>(img_t, seg_cnt, segs, epw, out_t);
    k_untranspose<<<dim3(NCELL / 32, C_DIM / 32, B_DIM), dim3(32, 8), 0, stream>>>(
        out_t, out);
}